// Round 13
// baseline (4418.956 us; speedup 1.0000x reference)
//
#include <hip/hip_runtime.h>

#define TSTEPS 2000
#define NBATCH 16
#define DDIM   512
#define HDIM   512
#define MTOT   (NBATCH * TSTEPS)
#define LEPS   1e-5f

typedef _Float16 f16x8 __attribute__((ext_vector_type(8)));
typedef _Float16 f16x4 __attribute__((ext_vector_type(4)));
typedef float    f32x4 __attribute__((ext_vector_type(4)));
typedef unsigned long long u64;
typedef unsigned u32;

// ---------------- Phase 1: w = BN(x @ W^T), f16 MFMA ----------------  (r4, verified ~60us)
__global__ __launch_bounds__(256) void gemm_bn_f16_kernel(
    const float* __restrict__ x, const float* __restrict__ W,
    const float* __restrict__ gamma, const float* __restrict__ beta,
    const float* __restrict__ rmean, const float* __restrict__ rvar,
    float* __restrict__ out_a, float* __restrict__ out_z)
{
  __shared__ _Float16 Asm[128 * 64];
  __shared__ _Float16 Bsm[128 * 64];
  const int tid  = threadIdx.x;
  const int wv   = tid >> 6;
  const int lane = tid & 63;
  const int c    = lane & 15;
  const int hi   = lane >> 4;
  const int m0   = blockIdx.x * 128;
  const int n0   = blockIdx.y * 128;

  float invg[2], mng[2], btg[2];
#pragma unroll
  for (int nt = 0; nt < 2; ++nt) {
    const int gc = n0 + wv * 32 + nt * 16 + c;
    invg[nt] = gamma[gc] * rsqrtf(rvar[gc] + LEPS);
    mng[nt]  = rmean[gc];
    btg[nt]  = beta[gc];
  }

  f32x4 acc[8][2];
#pragma unroll
  for (int mt = 0; mt < 8; ++mt)
#pragma unroll
    for (int nt = 0; nt < 2; ++nt) acc[mt][nt] = (f32x4){0.f, 0.f, 0.f, 0.f};

  const int sf4  = tid & 15;
  const int srow = tid >> 4;

  for (int k0 = 0; k0 < DDIM; k0 += 64) {
    __syncthreads();
#pragma unroll
    for (int p = 0; p < 8; ++p) {
      const int r = p * 16 + srow;
      float4 va = *(const float4*)&x[(size_t)(m0 + r) * DDIM + k0 + sf4 * 4];
      float4 vb = *(const float4*)&W[(size_t)(n0 + r) * DDIM + k0 + sf4 * 4];
      f16x4 ha, hb;
      ha[0] = (_Float16)va.x; ha[1] = (_Float16)va.y;
      ha[2] = (_Float16)va.z; ha[3] = (_Float16)va.w;
      hb[0] = (_Float16)vb.x; hb[1] = (_Float16)vb.y;
      hb[2] = (_Float16)vb.z; hb[3] = (_Float16)vb.w;
      const int byo = r * 128 + ((sf4 * 8) ^ ((r & 7) << 4));
      *(f16x4*)((char*)Asm + byo) = ha;
      *(f16x4*)((char*)Bsm + byo) = hb;
    }
    __syncthreads();
#pragma unroll
    for (int kc = 0; kc < 2; ++kc) {
      const int kof = (kc * 32 + hi * 8) * 2;
      f16x8 bfr[2];
#pragma unroll
      for (int nt = 0; nt < 2; ++nt) {
        const int rr = wv * 32 + nt * 16 + c;
        bfr[nt] = *(const f16x8*)((const char*)Bsm + rr * 128 + (kof ^ ((rr & 7) << 4)));
      }
#pragma unroll
      for (int mt = 0; mt < 8; ++mt) {
        const int rr = mt * 16 + c;
        f16x8 afr = *(const f16x8*)((const char*)Asm + rr * 128 + (kof ^ ((rr & 7) << 4)));
        acc[mt][0] = __builtin_amdgcn_mfma_f32_16x16x32_f16(afr, bfr[0], acc[mt][0], 0, 0, 0);
        acc[mt][1] = __builtin_amdgcn_mfma_f32_16x16x32_f16(afr, bfr[1], acc[mt][1], 0, 0, 0);
      }
    }
  }

  const bool isA = (n0 < HDIM);
  float* dst = isA ? out_a : out_z;
  const int cb = isA ? n0 : (n0 - HDIM);
#pragma unroll
  for (int mt = 0; mt < 8; ++mt)
#pragma unroll
    for (int nt = 0; nt < 2; ++nt) {
      const int col = cb + wv * 32 + nt * 16 + c;
#pragma unroll
      for (int i = 0; i < 4; ++i) {
        const int row = m0 + mt * 16 + hi * 4 + i;
        dst[(size_t)row * HDIM + col] = (acc[mt][nt][i] - mng[nt]) * invg[nt] + btg[nt];
      }
    }
}

// ---------------- Phase 2: champion structure + scope-lowered exchange ----------------
// 128 blocks = 16 batches x 8 groups, congruent mapping bid = g*16+b (same-XCD
// clusters per r11 evidence). NEW: runtime visibility probe -- if all 8 blocks
// of a batch demonstrate mutual workgroup-scope atomic visibility (=> same XCD
// L2), the h-exchange runs via L2-point atomics (wg-scope store + wg-scope
// fetch_add(0) RMW poll, both bypass L1, RT ~200cy) instead of agent-scope
// MALL atomics (~900cy). Fallback: proven agent-scope path. Output bit-identical
// either way; no placement assumption (G16-safe), probe is bounded (no deadlock).
// Split tag/data protocol: per-publisher tag line (1 RMW/wave/round spin) +
// u32 data atoms at stride 4 (spread L2 atomic channels). Explicit
// s_waitcnt vmcnt(0) between the wave's data stores and its tag store.
// Slot-overwrite safety: same induction as r3 (tag t+1 stored only after the
// block passed bar1(t), i.e. after ALL its reads of slot t&1 completed).
// RMW addend is runtime-zero (bid>>30) so InstCombine can't fold fetch_add(0)
// into a (stale-L1-prone) atomic load.
__global__ __launch_bounds__(512, 2) void rnn_sync_kernel(
    const float* __restrict__ U,
    float* __restrict__ out,              // [16][2000][512]: w_a in, h out (in place)
    const float* __restrict__ wz,         // [16][2000][512]
    u32* __restrict__ xdata,              // [2][16][512*4] f32-bits, stride 4
    u32* __restrict__ xtag,               // [2][16][8] stride-32 (128B/line)
    u64* __restrict__ probe,              // [16][8] stride-16 (128B/line)
    u32* __restrict__ prep)               // [16][8] stride-32 (128B/line)
{
  __shared__ __align__(16) _Float16 hbuf[512];
  __shared__ float hf32[512];
  __shared__ float gbuf[128];
  __shared__ float waring[8][64];
  __shared__ float wzring[8][64];
  __shared__ int s_fast;

  const int tid  = threadIdx.x;
  const int w    = tid >> 6;
  const int lane = tid & 63;
  const int c    = lane & 15;
  const int hi   = lane >> 4;
  const int bid  = blockIdx.x;
  const int b    = bid & 15, g = bid >> 4;   // congruent mapping (champion)
  const int g0   = g * 64;
  const size_t obase = (size_t)b * TSTEPS * HDIM;
  const u32 uZ   = ((u32)blockIdx.x) >> 30;  // runtime 0, compile-time unknown
  const u64 uZ64 = (u64)uZ;

  // ---- runtime same-L2 visibility probe & cluster handshake ----
  if (tid == 0)
    __hip_atomic_store(&probe[(b * 8 + g) * 16], 1ull,
                       __ATOMIC_RELAXED, __HIP_MEMORY_SCOPE_WORKGROUP);
  bool okl = true;
  if (tid < 8) {
    u64* pp = &probe[(b * 8 + tid) * 16];
    u64 v = 0; int it = 0;
    do {
      v = __hip_atomic_fetch_add(pp, uZ64, __ATOMIC_RELAXED, __HIP_MEMORY_SCOPE_WORKGROUP);
    } while (v == 0 && ++it < 2000);
    okl = (v != 0);
  }
  if (w == 0) {
    const bool all8 = __all(okl);
    if (lane == 0)
      __hip_atomic_store(&prep[(b * 8 + g) * 32], all8 ? 2u : 1u,
                         __ATOMIC_RELAXED, __HIP_MEMORY_SCOPE_AGENT);
  }
  if (tid < 8) {
    u32 r;
    do {
      r = __hip_atomic_load(&prep[(b * 8 + tid) * 32],
                            __ATOMIC_RELAXED, __HIP_MEMORY_SCOPE_AGENT);
    } while (r == 0);
    okl = (r == 2);
  } else {
    okl = true;
  }
  if (w == 0) {
    const bool all8 = __all(okl);
    if (lane == 0) s_fast = all8 ? 1 : 0;
  }

  // persistent U B-fragments: wave w owns local gate cols [w*16, w*16+16)
  const int L    = w * 16 + c;
  const int urow = (L < 64) ? (g0 + L) : (HDIM + g0 + (L - 64));
  f16x8 ufrag[16];
  {
    const float* up = &U[(size_t)urow * HDIM + hi * 8];
#pragma unroll
    for (int kt = 0; kt < 16; ++kt) {
      float4 lo = *(const float4*)&up[kt * 32];
      float4 h4 = *(const float4*)&up[kt * 32 + 4];
      f16x8 f;
      f[0] = (_Float16)lo.x; f[1] = (_Float16)lo.y;
      f[2] = (_Float16)lo.z; f[3] = (_Float16)lo.w;
      f[4] = (_Float16)h4.x; f[5] = (_Float16)h4.y;
      f[6] = (_Float16)h4.z; f[7] = (_Float16)h4.w;
      ufrag[kt] = f;
    }
  }

  hbuf[tid] = (_Float16)0.f;
  hf32[tid] = 0.f;
#pragma unroll
  for (int p = 0; p < 3; ++p) {
    if (tid < 64)        waring[p][tid]      = out[obase + (size_t)p * HDIM + g0 + tid];
    else if (tid < 128)  wzring[p][tid - 64] = wz [obase + (size_t)p * HDIM + g0 + (tid - 64)];
  }
  float pv_carry = 0.f;                      // holds w[t+3] entering iteration t
  if (tid < 64)       pv_carry = out[obase + (size_t)3 * HDIM + g0 + tid];
  else if (tid < 128) pv_carry = wz [obase + (size_t)3 * HDIM + g0 + (tid - 64)];
  __syncthreads();                           // also publishes s_fast
  const bool fast = (s_fast != 0);

  for (int t = 0; t < TSTEPS; ++t) {
    // ---- A: tag spin (1 RMW-lane per wave) + data read + LDS write ----
    if (t > 0) {
      const u32 want = (u32)t;
      u32* tp = xtag + (((size_t)(t & 1) * NBATCH + b) * 8 + w) * 32;
      u32 tv;
      if (fast) {
        do {
          u32 x0 = (lane == 0)
              ? __hip_atomic_fetch_add(tp, uZ, __ATOMIC_RELAXED, __HIP_MEMORY_SCOPE_WORKGROUP)
              : 0u;
          tv = (u32)__builtin_amdgcn_readfirstlane((int)x0);
        } while (tv != want);
      } else {
        do {
          u32 x0 = (lane == 0)
              ? __hip_atomic_load(tp, __ATOMIC_RELAXED, __HIP_MEMORY_SCOPE_AGENT)
              : 0u;
          tv = (u32)__builtin_amdgcn_readfirstlane((int)x0);
        } while (tv != want);
      }
      u32* dp = xdata + ((size_t)(t & 1) * NBATCH + b) * 2048 + tid * 4;
      const u32 dv = fast
          ? __hip_atomic_fetch_add(dp, uZ, __ATOMIC_RELAXED, __HIP_MEMORY_SCOPE_WORKGROUP)
          : __hip_atomic_load(dp, __ATOMIC_RELAXED, __HIP_MEMORY_SCOPE_AGENT);
      const float hv = __uint_as_float(dv);
      hbuf[tid] = (_Float16)hv;
      hf32[tid] = hv;
    }
    __syncthreads();                                   // bar1: hbuf/hf32 ready

    const float hold = (tid < 64) ? hf32[g0 + tid] : 0.f;  // read before bar2

    // ---- B: gates (2 interleaved MFMA chains, champion) ----
    f32x4 acc0 = {0.f, 0.f, 0.f, 0.f};
    f32x4 acc1 = {0.f, 0.f, 0.f, 0.f};
#pragma unroll
    for (int ktg = 0; ktg < 4; ++ktg) {
      f16x8 af[4];
#pragma unroll
      for (int q = 0; q < 4; ++q)
        af[q] = *(const f16x8*)&hbuf[ktg * 128 + q * 32 + hi * 8];
      acc0 = __builtin_amdgcn_mfma_f32_16x16x32_f16(af[0], ufrag[ktg * 4 + 0], acc0, 0, 0, 0);
      acc1 = __builtin_amdgcn_mfma_f32_16x16x32_f16(af[1], ufrag[ktg * 4 + 1], acc1, 0, 0, 0);
      acc0 = __builtin_amdgcn_mfma_f32_16x16x32_f16(af[2], ufrag[ktg * 4 + 2], acc0, 0, 0, 0);
      acc1 = __builtin_amdgcn_mfma_f32_16x16x32_f16(af[3], ufrag[ktg * 4 + 3], acc1, 0, 0, 0);
    }
    if (lane < 16) gbuf[w * 16 + lane] = acc0[0] + acc1[0];
    __syncthreads();                                   // bar2: gbuf ready

    // ---- C: h update + data publish + (vmcnt drain) + tag publish ----
    if (tid < 64) {
      const float a  = gbuf[tid]      + waring[t & 7][tid];
      const float zg = gbuf[64 + tid] + wzring[t & 7][tid];
      const float z  = 1.f / (1.f + expf(-zg));
      const float hc = fmaxf(a, 0.f);
      const float hn = z * hold + (1.f - z) * hc;
      if (t + 1 < TSTEPS) {
        u32* dq = xdata + ((size_t)((t + 1) & 1) * NBATCH + b) * 2048 + (g0 + tid) * 4;
        if (fast)
          __hip_atomic_store(dq, __float_as_uint(hn), __ATOMIC_RELAXED, __HIP_MEMORY_SCOPE_WORKGROUP);
        else
          __hip_atomic_store(dq, __float_as_uint(hn), __ATOMIC_RELAXED, __HIP_MEMORY_SCOPE_AGENT);
        asm volatile("s_waitcnt vmcnt(0)" ::: "memory");   // wave0's 64 data stores acked
        if (tid == 0) {
          u32* tq = xtag + (((size_t)((t + 1) & 1) * NBATCH + b) * 8 + g) * 32;
          if (fast)
            __hip_atomic_store(tq, (u32)(t + 1), __ATOMIC_RELAXED, __HIP_MEMORY_SCOPE_WORKGROUP);
          else
            __hip_atomic_store(tq, (u32)(t + 1), __ATOMIC_RELAXED, __HIP_MEMORY_SCOPE_AGENT);
        }
      }
      out[obase + (size_t)t * HDIM + g0 + tid] = hn;   // off critical path
    }

    // ---- D: hidden tail -- ring write (carry from last iter) + NEW issue ----
    if (t + 3 < TSTEPS) {
      if (tid < 64)       waring[(t + 3) & 7][tid]      = pv_carry;
      else if (tid < 128) wzring[(t + 3) & 7][tid - 64] = pv_carry;
    }
    if (t + 4 < TSTEPS) {   // issue w[t+4]; vmcnt-waited a full iteration later
      if (tid < 64)       pv_carry = out[obase + (size_t)(t + 4) * HDIM + g0 + tid];
      else if (tid < 128) pv_carry = wz [obase + (size_t)(t + 4) * HDIM + g0 + (tid - 64)];
    }
  }
}

extern "C" void kernel_launch(void* const* d_in, const int* in_sizes, int n_in,
                              void* d_out, int out_size, void* d_ws, size_t ws_size,
                              hipStream_t stream) {
  const float* x     = (const float*)d_in[0];
  const float* W     = (const float*)d_in[1];
  const float* U     = (const float*)d_in[2];
  const float* gamma = (const float*)d_in[3];
  const float* beta  = (const float*)d_in[4];
  const float* rmean = (const float*)d_in[5];
  const float* rvar  = (const float*)d_in[6];
  float* out = (float*)d_out;

  const size_t wz_bytes = (size_t)MTOT * HDIM * sizeof(float);   // 65,536,000
  float* wzp   = (float*)d_ws;
  char*  base  = (char*)d_ws + wz_bytes;
  u32*   xdata = (u32*)(base);                     // 2*16*2048*4  = 256 KB
  u32*   xtag  = (u32*)(base + 262144);            // 2*16*8*128B  =  32 KB
  u64*   probe = (u64*)(base + 262144 + 32768);    // 128*128B     =  16 KB
  u32*   prep  = (u32*)(base + 262144 + 32768 + 16384); // 16 KB

  hipMemsetAsync(base, 0, 262144 + 32768 + 16384 + 16384, stream);

  dim3 g1(MTOT / 128, (HDIM * 2) / 128), b1(256);
  gemm_bn_f16_kernel<<<g1, b1, 0, stream>>>(x, W, gamma, beta, rmean, rvar, out, wzp);
  rnn_sync_kernel<<<dim3(128), dim3(512), 0, stream>>>(U, out, wzp, xdata, xtag, probe, prep);
}

// Round 14
// 2640.351 us; speedup vs baseline: 1.6736x; 1.6736x over previous
//
#include <hip/hip_runtime.h>

#define TSTEPS 2000
#define NBATCH 16
#define DDIM   512
#define HDIM   512
#define MTOT   (NBATCH * TSTEPS)
#define LEPS   1e-5f

typedef _Float16 f16x8 __attribute__((ext_vector_type(8)));
typedef _Float16 f16x4 __attribute__((ext_vector_type(4)));
typedef float    f32x4 __attribute__((ext_vector_type(4)));
typedef unsigned long long u64;

// ---------------- Phase 1: w = BN(x @ W^T), f16 MFMA ----------------  (r4, verified ~60us)
__global__ __launch_bounds__(256) void gemm_bn_f16_kernel(
    const float* __restrict__ x, const float* __restrict__ W,
    const float* __restrict__ gamma, const float* __restrict__ beta,
    const float* __restrict__ rmean, const float* __restrict__ rvar,
    float* __restrict__ out_a, float* __restrict__ out_z)
{
  __shared__ _Float16 Asm[128 * 64];
  __shared__ _Float16 Bsm[128 * 64];
  const int tid  = threadIdx.x;
  const int wv   = tid >> 6;
  const int lane = tid & 63;
  const int c    = lane & 15;
  const int hi   = lane >> 4;
  const int m0   = blockIdx.x * 128;
  const int n0   = blockIdx.y * 128;

  float invg[2], mng[2], btg[2];
#pragma unroll
  for (int nt = 0; nt < 2; ++nt) {
    const int gc = n0 + wv * 32 + nt * 16 + c;
    invg[nt] = gamma[gc] * rsqrtf(rvar[gc] + LEPS);
    mng[nt]  = rmean[gc];
    btg[nt]  = beta[gc];
  }

  f32x4 acc[8][2];
#pragma unroll
  for (int mt = 0; mt < 8; ++mt)
#pragma unroll
    for (int nt = 0; nt < 2; ++nt) acc[mt][nt] = (f32x4){0.f, 0.f, 0.f, 0.f};

  const int sf4  = tid & 15;
  const int srow = tid >> 4;

  for (int k0 = 0; k0 < DDIM; k0 += 64) {
    __syncthreads();
#pragma unroll
    for (int p = 0; p < 8; ++p) {
      const int r = p * 16 + srow;
      float4 va = *(const float4*)&x[(size_t)(m0 + r) * DDIM + k0 + sf4 * 4];
      float4 vb = *(const float4*)&W[(size_t)(n0 + r) * DDIM + k0 + sf4 * 4];
      f16x4 ha, hb;
      ha[0] = (_Float16)va.x; ha[1] = (_Float16)va.y;
      ha[2] = (_Float16)va.z; ha[3] = (_Float16)va.w;
      hb[0] = (_Float16)vb.x; hb[1] = (_Float16)vb.y;
      hb[2] = (_Float16)vb.z; hb[3] = (_Float16)vb.w;
      const int byo = r * 128 + ((sf4 * 8) ^ ((r & 7) << 4));
      *(f16x4*)((char*)Asm + byo) = ha;
      *(f16x4*)((char*)Bsm + byo) = hb;
    }
    __syncthreads();
#pragma unroll
    for (int kc = 0; kc < 2; ++kc) {
      const int kof = (kc * 32 + hi * 8) * 2;
      f16x8 bfr[2];
#pragma unroll
      for (int nt = 0; nt < 2; ++nt) {
        const int rr = wv * 32 + nt * 16 + c;
        bfr[nt] = *(const f16x8*)((const char*)Bsm + rr * 128 + (kof ^ ((rr & 7) << 4)));
      }
#pragma unroll
      for (int mt = 0; mt < 8; ++mt) {
        const int rr = mt * 16 + c;
        f16x8 afr = *(const f16x8*)((const char*)Asm + rr * 128 + (kof ^ ((rr & 7) << 4)));
        acc[mt][0] = __builtin_amdgcn_mfma_f32_16x16x32_f16(afr, bfr[0], acc[mt][0], 0, 0, 0);
        acc[mt][1] = __builtin_amdgcn_mfma_f32_16x16x32_f16(afr, bfr[1], acc[mt][1], 0, 0, 0);
      }
    }
  }

  const bool isA = (n0 < HDIM);
  float* dst = isA ? out_a : out_z;
  const int cb = isA ? n0 : (n0 - HDIM);
#pragma unroll
  for (int mt = 0; mt < 8; ++mt)
#pragma unroll
    for (int nt = 0; nt < 2; ++nt) {
      const int col = cb + wv * 32 + nt * 16 + c;
#pragma unroll
      for (int i = 0; i < 4; ++i) {
        const int row = m0 + mt * 16 + hi * 4 + i;
        dst[(size_t)row * HDIM + col] = (acc[mt][nt][i] - mng[nt]) * invg[nt] + btg[nt];
      }
    }
}

// ---------------- Phase 2: champion r12 configuration (communication floor) ----------
// 128 blocks = 16 batches x 8 groups, CONGRUENT mapping bid = g*16+b (same-XCD
// clusters; r11 proved spread mapping worse, r13 proved wg-scope L2 RMW
// exchange far worse -- device-memory atomic RMWs execute at the HBM-side
// coherence point, WRITE_SIZE 192MB->2.5GB). Protocol: {tag,f32 h} packed
// 8-byte relaxed agent-scope atoms, equality spin on parity slots, fence-free
// (r3 safety argument). Per step: spin+LDS write | bar1 | 2 interleaved MFMA
// chains -> gbuf | bar2 | wave-0 gate math, out-store, publish | hidden tail
// (ring write from carried prefetch + issue w[t+4]).
// Floor accounting (r4-r13 falsification ladder): per-step ~3100cy =
// agent-scope store->load visibility + poll quantization (~2100cy, MALL-class,
// irreducible at source level) + compute chain (~1000cy, all micro-variants
// measured null). Alternatives enumerated and all worse: flags+fence (r1),
// 3-deep poll (r8), f16 pre-activation publish (r9), lockstep multi-batch
// (r10), XCD spread (r11), wg-scope RMW (r13).
__global__ __launch_bounds__(512, 2) void rnn_sync_kernel(
    const float* __restrict__ U,
    float* __restrict__ out,              // [16][2000][512]: w_a in, h out (in place)
    const float* __restrict__ wz,         // [16][2000][512]
    u64* __restrict__ xbuf)               // [2][16][512] {tag,val} -- memset 0 per launch
{
  __shared__ __align__(16) _Float16 hbuf[512];
  __shared__ float hf32[512];
  __shared__ float gbuf[128];
  __shared__ float waring[8][64];
  __shared__ float wzring[8][64];

  const int tid  = threadIdx.x;
  const int w    = tid >> 6;
  const int lane = tid & 63;
  const int c    = lane & 15;
  const int hi   = lane >> 4;
  const int bid  = blockIdx.x;
  const int b    = bid & 15, g = bid >> 4;   // congruent mapping (champion)
  const int g0   = g * 64;
  const size_t obase = (size_t)b * TSTEPS * HDIM;

  // persistent U B-fragments: wave w owns local gate cols [w*16, w*16+16)
  const int L    = w * 16 + c;
  const int urow = (L < 64) ? (g0 + L) : (HDIM + g0 + (L - 64));
  f16x8 ufrag[16];
  {
    const float* up = &U[(size_t)urow * HDIM + hi * 8];
#pragma unroll
    for (int kt = 0; kt < 16; ++kt) {
      float4 lo = *(const float4*)&up[kt * 32];
      float4 h4 = *(const float4*)&up[kt * 32 + 4];
      f16x8 f;
      f[0] = (_Float16)lo.x; f[1] = (_Float16)lo.y;
      f[2] = (_Float16)lo.z; f[3] = (_Float16)lo.w;
      f[4] = (_Float16)h4.x; f[5] = (_Float16)h4.y;
      f[6] = (_Float16)h4.z; f[7] = (_Float16)h4.w;
      ufrag[kt] = f;
    }
  }

  hbuf[tid] = (_Float16)0.f;
  hf32[tid] = 0.f;
#pragma unroll
  for (int p = 0; p < 3; ++p) {
    if (tid < 64)        waring[p][tid]      = out[obase + (size_t)p * HDIM + g0 + tid];
    else if (tid < 128)  wzring[p][tid - 64] = wz [obase + (size_t)p * HDIM + g0 + (tid - 64)];
  }
  float pv_carry = 0.f;                      // holds w[t+3] entering iteration t
  if (tid < 64)       pv_carry = out[obase + (size_t)3 * HDIM + g0 + tid];
  else if (tid < 128) pv_carry = wz [obase + (size_t)3 * HDIM + g0 + (tid - 64)];
  __syncthreads();

  for (int t = 0; t < TSTEPS; ++t) {
    // ---- A: acquire h_t -- spin + LDS write ONLY before bar1 ----
    if (t > 0) {
      u64* xb = &xbuf[((size_t)(t & 1) * NBATCH + b) * HDIM];
      u64 v;
      do {
        v = __hip_atomic_load(&xb[tid], __ATOMIC_RELAXED, __HIP_MEMORY_SCOPE_AGENT);
      } while ((unsigned)(v >> 32) != (unsigned)t);
      const float hv = __uint_as_float((unsigned)v);
      hbuf[tid] = (_Float16)hv;
      hf32[tid] = hv;
    }
    __syncthreads();                                   // bar1: hbuf/hf32 ready

    const float hold = (tid < 64) ? hf32[g0 + tid] : 0.f;  // read before bar2

    // ---- B: gates (2 interleaved MFMA chains) ----
    f32x4 acc0 = {0.f, 0.f, 0.f, 0.f};
    f32x4 acc1 = {0.f, 0.f, 0.f, 0.f};
#pragma unroll
    for (int ktg = 0; ktg < 4; ++ktg) {
      f16x8 af[4];
#pragma unroll
      for (int q = 0; q < 4; ++q)
        af[q] = *(const f16x8*)&hbuf[ktg * 128 + q * 32 + hi * 8];
      acc0 = __builtin_amdgcn_mfma_f32_16x16x32_f16(af[0], ufrag[ktg * 4 + 0], acc0, 0, 0, 0);
      acc1 = __builtin_amdgcn_mfma_f32_16x16x32_f16(af[1], ufrag[ktg * 4 + 1], acc1, 0, 0, 0);
      acc0 = __builtin_amdgcn_mfma_f32_16x16x32_f16(af[2], ufrag[ktg * 4 + 2], acc0, 0, 0, 0);
      acc1 = __builtin_amdgcn_mfma_f32_16x16x32_f16(af[3], ufrag[ktg * 4 + 3], acc1, 0, 0, 0);
    }
    if (lane < 16) gbuf[w * 16 + lane] = acc0[0] + acc1[0];
    __syncthreads();                                   // bar2: gbuf ready

    // ---- C: h update + publish (out store, then publish) ----
    if (tid < 64) {
      const float a  = gbuf[tid]      + waring[t & 7][tid];
      const float zg = gbuf[64 + tid] + wzring[t & 7][tid];
      const float z  = 1.f / (1.f + expf(-zg));
      const float hc = fmaxf(a, 0.f);
      const float hn = z * hold + (1.f - z) * hc;
      out[obase + (size_t)t * HDIM + g0 + tid] = hn;
      if (t + 1 < TSTEPS) {
        const u64 pkt = ((u64)(unsigned)(t + 1) << 32) | (u64)__float_as_uint(hn);
        __hip_atomic_store(&xbuf[((size_t)((t + 1) & 1) * NBATCH + b) * HDIM + g0 + tid],
                           pkt, __ATOMIC_RELAXED, __HIP_MEMORY_SCOPE_AGENT);
      }
    }

    // ---- D: hidden tail -- ring write (carry from last iter) + NEW issue ----
    if (t + 3 < TSTEPS) {
      if (tid < 64)       waring[(t + 3) & 7][tid]      = pv_carry;
      else if (tid < 128) wzring[(t + 3) & 7][tid - 64] = pv_carry;
    }
    if (t + 4 < TSTEPS) {   // issue w[t+4]; vmcnt-waited a full iteration later
      if (tid < 64)       pv_carry = out[obase + (size_t)(t + 4) * HDIM + g0 + tid];
      else if (tid < 128) pv_carry = wz [obase + (size_t)(t + 4) * HDIM + g0 + (tid - 64)];
    }
  }
}

extern "C" void kernel_launch(void* const* d_in, const int* in_sizes, int n_in,
                              void* d_out, int out_size, void* d_ws, size_t ws_size,
                              hipStream_t stream) {
  const float* x     = (const float*)d_in[0];
  const float* W     = (const float*)d_in[1];
  const float* U     = (const float*)d_in[2];
  const float* gamma = (const float*)d_in[3];
  const float* beta  = (const float*)d_in[4];
  const float* rmean = (const float*)d_in[5];
  const float* rvar  = (const float*)d_in[6];
  float* out = (float*)d_out;

  const size_t wz_bytes = (size_t)MTOT * HDIM * sizeof(float);   // 65,536,000
  float* wzp = (float*)d_ws;
  u64*  xbuf = (u64*)((char*)d_ws + wz_bytes);                   // [2][16][512] u64

  hipMemsetAsync(xbuf, 0, (size_t)2 * NBATCH * HDIM * sizeof(u64), stream);

  dim3 g1(MTOT / 128, (HDIM * 2) / 128), b1(256);
  gemm_bn_f16_kernel<<<g1, b1, 0, stream>>>(x, W, gamma, beta, rmean, rvar, out, wzp);
  rnn_sync_kernel<<<dim3(128), dim3(512), 0, stream>>>(U, out, wzp, xbuf);
}